// Round 8
// baseline (337.429 us; speedup 1.0000x reference)
//
#include <hip/hip_runtime.h>

// Problem constants
static constexpr int Nn_ = 32, Cc_ = 64, Hh_ = 64, Ww_ = 64;
static constexpr int K_ = 512;
static constexpr int HW_ = Hh_ * Ww_;             // 4096
static constexpr int CHW_ = Cc_ * HW_;            // 262144
static constexpr int T_ = Nn_ * Hh_ * Ww_;        // 131072 tokens
static constexpr int OUT_ELEMS = Nn_ * Cc_ * Hh_ * Ww_;  // 8388608
// d_out layout: [out][codebook_new (32768)][N_new (512)][m_new (32768)]
static constexpr int OFF_CB = OUT_ELEMS;
static constexpr int OFF_N  = OUT_ELEMS + 32768;
static constexpr int OFF_M  = OUT_ELEMS + 32768 + 512;

static constexpr int S_ = 32;   // stats slices == images

// ws layout (floats):
// [0, T_)        idx per token (int)
// [T_, T_+512)   cnorm2
// [WS_PSUM, +S_*512*64)  per-slice partial sums [s][c][k]
// [WS_PCNT, +S_*512)     per-slice partial counts [s][k]
static constexpr int WS_IDX   = 0;
static constexpr int WS_CNORM = T_;
static constexpr int WS_PSUM  = T_ + 512;
static constexpr int WS_PCNT  = WS_PSUM + S_ * K_ * Cc_;

// K0: |c|^2 per codeword
__global__ __launch_bounds__(256) void k_prep(const float* __restrict__ cb,
                                              float* __restrict__ ws) {
    int i = blockIdx.x * 256 + threadIdx.x;
    if (i < K_) {
        const float* r = cb + i * 64;
        float a = 0.f;
#pragma unroll
        for (int j = 0; j < 64; ++j) a = fmaf(r[j], r[j], a);
        ws[WS_CNORM + i] = a;
    }
}

// K1: block = one (n,h) row (64 tokens), 8 waves; wave wi owns 64 codewords.
// Register profile inverted vs R2-R7: per-thread persistent state is acc[16]
// (accumulators - not rematerializable) + best(d,k). x lives in LDS (stride
// 65 => conflict-free), read 4 floats at a time; cb comes via the scalar
// path (readfirstlane -> uniform -> s_load). 16 independent FMA chains.
// Argmin: in-reg per lane (ascending k, strict <) then cross-wave
// lexicographic (sortable_d, k) u64 min == np.argmin first-min exactly.
// Epilogue absorbs the old k_merge (padded-LDS transpose q-write).
__global__ __launch_bounds__(512) void k_assign(const float* __restrict__ x,
                                                const float* __restrict__ cb,
                                                const float* __restrict__ ws_cn,
                                                float* __restrict__ ws,
                                                float* __restrict__ out) {
    __shared__ float xs[64][65];                 // [token][chan] / later [chan][token] tile
    __shared__ unsigned long long redk[8][64];   // per-wave candidate per token
    __shared__ int bi_s[64];

    const float* __restrict__ cnorm2 = ws_cn + WS_CNORM;
    const int row  = blockIdx.x;          // n*64 + h
    const int tid  = threadIdx.x;
    const int lane = tid & 63;            // token-in-row during main loop
    const int wiv  = tid >> 6;            // wave index 0..7 (divergent view)
    const int wi_s = __builtin_amdgcn_readfirstlane(wiv);  // SGPR: uniform k-range
    const int n = row >> 6, h = row & 63;
    const int xbase = n * CHW_ + h * Ww_;

    // Stage x row-tile: 4096 floats, coalesced global, conflict-free LDS
    // (store addr = w*65 + c; 65 coprime 32 => banks spread).
#pragma unroll
    for (int it = 0; it < 8; ++it) {
        int id8 = it * 512 + tid;
        int c = id8 >> 6, w = id8 & 63;
        xs[w][c] = x[xbase + c * HW_ + w];
    }
    __syncthreads();

    const int k0 = wi_s * 64;
    float bestd = __builtin_inff();
    int   bestk = k0;

#pragma unroll 1
    for (int kb = 0; kb < 4; ++kb) {
        const int kbase = k0 + kb * 16;
        float acc[16];
#pragma unroll
        for (int kk = 0; kk < 16; ++kk) acc[kk] = 0.f;

#pragma unroll 2
        for (int cc = 0; cc < 16; ++cc) {
            // 4 x-values from LDS (addr = lane*65 + c: conflict-free)
            float x0 = xs[lane][cc * 4 + 0];
            float x1 = xs[lane][cc * 4 + 1];
            float x2 = xs[lane][cc * 4 + 2];
            float x3 = xs[lane][cc * 4 + 3];
#pragma unroll
            for (int kk = 0; kk < 16; ++kk) {
                const float* __restrict__ cr = cb + (kbase + kk) * 64 + cc * 4;  // uniform -> s_load
                float a = acc[kk];
                a = fmaf(cr[0], x0, a);
                a = fmaf(cr[1], x1, a);
                a = fmaf(cr[2], x2, a);
                a = fmaf(cr[3], x3, a);
                acc[kk] = a;
            }
        }
        // d = |c|^2 - 2*x.c  (token-constant |x|^2 dropped: argmin-invariant)
#pragma unroll
        for (int kk = 0; kk < 16; ++kk) {
            float d = fmaf(-2.0f, acc[kk], cnorm2[kbase + kk]);
            if (d < bestd) { bestd = d; bestk = kbase + kk; }  // ascending k, strict <
        }
    }

    // Pack (sortable_d, k): u64 min == lexicographic (d, k) min == np first-min
    unsigned int db = __float_as_uint(bestd);
    db = (db & 0x80000000u) ? ~db : (db | 0x80000000u);
    redk[wiv][lane] = ((unsigned long long)db << 32) | (unsigned int)bestk;
    __syncthreads();

    if (tid < 64) {
        unsigned long long b = redk[0][tid];
#pragma unroll
        for (int w = 1; w < 8; ++w) {
            unsigned long long v = redk[w][tid];
            b = (v < b) ? v : b;
        }
        int bi = (int)(b & 0xffffffffu);
        ((int*)(ws + WS_IDX))[row * 64 + tid] = bi;   // coalesced
        bi_s[tid] = bi;
    }
    __syncthreads();

    // q-gather + transpose (reuse xs as tile[chan][token]): lanes=channels read
    // one 256B cb row per token; both LDS phases conflict-free (65 stride).
#pragma unroll
    for (int jj = 0; jj < 8; ++jj) {
        int tt = wiv * 8 + jj;
        xs[lane][tt] = cb[bi_s[tt] * 64 + lane];
    }
    __syncthreads();
#pragma unroll
    for (int jj = 0; jj < 8; ++jj) {
        int c = wiv * 8 + jj;
        out[xbase + c * HW_ + lane] = xs[c][lane];    // coalesced per channel
    }
}

// K2: block = (channel c, image s). float4/int4 coalesced reads, LDS histogram.
__global__ __launch_bounds__(256) void k_stats(const float* __restrict__ x,
                                               const float* __restrict__ ws_ro,
                                               float* __restrict__ ws) {
    const int* __restrict__ idx = (const int*)(ws_ro + WS_IDX);
    __shared__ float hist[512];
    __shared__ float hcnt[512];

    const int c = blockIdx.x & 63;
    const int s = blockIdx.x >> 6;
    const int tid = threadIdx.x;
    const bool docnt = (c == 0);

    hist[tid] = 0.f; hist[tid + 256] = 0.f;
    hcnt[tid] = 0.f; hcnt[tid + 256] = 0.f;
    __syncthreads();

    const float4* __restrict__ xc4 = (const float4*)(x + s * CHW_ + c * HW_);
    const int4*   __restrict__ id4 = (const int4*)(idx + s * HW_);
#pragma unroll
    for (int it = 0; it < 4; ++it) {
        int i = it * 256 + tid;
        int4   ii = id4[i];            // coalesced 16B, L2-hot
        float4 xv = xc4[i];            // coalesced 16B
        atomicAdd(&hist[ii.x], xv.x);
        atomicAdd(&hist[ii.y], xv.y);
        atomicAdd(&hist[ii.z], xv.z);
        atomicAdd(&hist[ii.w], xv.w);
        if (docnt) {
            atomicAdd(&hcnt[ii.x], 1.0f);
            atomicAdd(&hcnt[ii.y], 1.0f);
            atomicAdd(&hcnt[ii.z], 1.0f);
            atomicAdd(&hcnt[ii.w], 1.0f);
        }
    }
    __syncthreads();

    float* psum = ws + WS_PSUM + s * (K_ * Cc_) + c * K_;
    psum[tid] = hist[tid];
    psum[tid + 256] = hist[tid + 256];
    if (docnt) {
        float* pc = ws + WS_PCNT + s * K_;
        pc[tid] = hcnt[tid];
        pc[tid + 256] = hcnt[tid + 256];
    }
}

// K3: reduce slices, finalize EMA states and codebook_new
__global__ __launch_bounds__(256) void k_final(const float* __restrict__ Ns,
                                               const float* __restrict__ ms,
                                               const float* __restrict__ ws,
                                               float* __restrict__ out) {
    int j = blockIdx.x * 256 + threadIdx.x;  // j = c*512 + k  (coalesced partial reads)
    int c = j >> 9, k = j & 511;

    float s = 0.f, cnt = 0.f;
    for (int sl = 0; sl < S_; ++sl) {
        s   += ws[WS_PSUM + sl * (K_ * Cc_) + j];
        cnt += ws[WS_PCNT + sl * K_ + k];
    }

    const float gamma = 0.99f;
    const float omg   = (float)(1.0 - 0.99);

    bool occ = cnt > 0.0f;
    float Nv = Ns[k];
    float Nnew = occ ? (Nv * gamma + cnt * omg) : Nv;

    int i = k * 64 + c;
    float mv = ms[i];
    float mnew = occ ? (mv * gamma + s * omg) : mv;

    out[OFF_CB + i] = mnew / Nnew;
    out[OFF_M  + i] = mnew;
    if (c == 0) out[OFF_N + k] = Nnew;
}

extern "C" void kernel_launch(void* const* d_in, const int* in_sizes, int n_in,
                              void* d_out, int out_size, void* d_ws, size_t ws_size,
                              hipStream_t stream) {
    const float* x  = (const float*)d_in[0];
    const float* cb = (const float*)d_in[1];
    const float* Ns = (const float*)d_in[2];
    const float* ms = (const float*)d_in[3];
    float* out = (float*)d_out;
    float* ws  = (float*)d_ws;

    hipLaunchKernelGGL(k_prep,   dim3(2),           dim3(256), 0, stream, cb, ws);
    hipLaunchKernelGGL(k_assign, dim3(Nn_ * Hh_),   dim3(512), 0, stream, x, cb, ws, ws, out);
    hipLaunchKernelGGL(k_stats,  dim3(S_ * Cc_),    dim3(256), 0, stream, x, ws, ws);
    hipLaunchKernelGGL(k_final,  dim3(32768 / 256), dim3(256), 0, stream, Ns, ms, ws, out);
}

// Round 9
// 299.028 us; speedup vs baseline: 1.1284x; 1.1284x over previous
//
#include <hip/hip_runtime.h>

// Problem constants
static constexpr int Nn_ = 32, Cc_ = 64, Hh_ = 64, Ww_ = 64;
static constexpr int K_ = 512;
static constexpr int HW_ = Hh_ * Ww_;             // 4096
static constexpr int CHW_ = Cc_ * HW_;            // 262144
static constexpr int T_ = Nn_ * Hh_ * Ww_;        // 131072 tokens
static constexpr int OUT_ELEMS = Nn_ * Cc_ * Hh_ * Ww_;  // 8388608
// d_out layout: [out][codebook_new (32768)][N_new (512)][m_new (32768)]
static constexpr int OFF_CB = OUT_ELEMS;
static constexpr int OFF_N  = OUT_ELEMS + 32768;
static constexpr int OFF_M  = OUT_ELEMS + 32768 + 512;

static constexpr int S_ = 32;   // stats slices == images

// ws layout (floats):
// [0, T_)        idx per token (int)
// [T_, T_+512)   (spare)
// [WS_PSUM, +S_*512*64)  per-slice partial sums [s][c][k]
// [WS_PCNT, +S_*512)     per-slice partial counts [s][k]
static constexpr int WS_IDX   = 0;
static constexpr int WS_PSUM  = T_ + 512;
static constexpr int WS_PCNT  = WS_PSUM + S_ * K_ * Cc_;

// K1: canonical register-tiled fp32 GEMM (learn_hip m33 shape — the one pattern
// this compiler provably does NOT spill). Block = one (n,h) row: M=64 tokens,
// K=64 channels staged once; N=512 codewords in 8 tiles of 64 restaged per
// tile. Thread = 4x4 accumulator tile, b128 LDS reads (pad +4 keeps 16B
// alignment AND rotates banks). cnorm computed per-tile from LDS (k_prep
// fused). Argmin = packed (sortable_d, k) u64 min == np.argmin first-min.
__global__ __launch_bounds__(256) void k_assign(const float* __restrict__ x,
                                                const float* __restrict__ cb,
                                                float* __restrict__ ws,
                                                float* __restrict__ out) {
    __shared__ alignas(16) float xs[64][68];   // [channel][token]
    __shared__ alignas(16) float cs[64][68];   // [codeword-in-tile][channel]
    __shared__ float pcn[4][64];
    __shared__ float cnorm_s[64];
    __shared__ unsigned long long red[64][17]; // [token][n-group], pad 17
    __shared__ int bi_s[64];

    const int row  = blockIdx.x;        // n*64 + h
    const int tid  = threadIdx.x;
    const int mg   = tid & 15;          // token-quad 0..15
    const int ng   = tid >> 4;          // codeword-quad 0..15
    const int lane = tid & 63;
    const int wv   = tid >> 6;          // wave 0..3
    const int n_i = row >> 6, h_i = row & 63;
    const int xbase = n_i * CHW_ + h_i * Ww_;

    // Stage xs[c][w]: 1024 float4, coalesced global, even bank spread.
#pragma unroll
    for (int stp = 0; stp < 4; ++stp) {
        int e = stp * 256 + tid;        // quad id
        int c = e >> 4, wq = e & 15;
        float4 v = *(const float4*)(x + xbase + c * HW_ + 4 * wq);
        *(float4*)&xs[c][4 * wq] = v;
    }

    unsigned long long bestP[4];
#pragma unroll
    for (int i = 0; i < 4; ++i) bestP[i] = ~0ull;

#pragma unroll 1
    for (int kt = 0; kt < 8; ++kt) {
        __syncthreads();                 // cs reusable; xs ready (kt=0)
        // Stage cs[r][c] for codewords kt*64..+63 (coalesced float4)
#pragma unroll
        for (int stp = 0; stp < 4; ++stp) {
            int e = stp * 256 + tid;
            int r = e >> 4, cq = e & 15;
            float4 v = *(const float4*)(cb + (kt * 64 + r) * 64 + 4 * cq);
            *(float4*)&cs[r][4 * cq] = v;
        }
        __syncthreads();

        // cnorm partials: wave wv covers channels [16wv,16wv+16) of row n=lane
        {
            float a = 0.f;
#pragma unroll
            for (int i = 0; i < 16; ++i) {
                float v = cs[lane][wv * 16 + i];
                a = fmaf(v, v, a);
            }
            pcn[wv][lane] = a;
        }
        __syncthreads();
        if (tid < 64)
            cnorm_s[tid] = (pcn[0][tid] + pcn[1][tid]) + (pcn[2][tid] + pcn[3][tid]);

        // 4x4 register tile over [token-quad mg] x [codeword-quad ng]
        float acc[4][4];
#pragma unroll
        for (int a = 0; a < 4; ++a)
#pragma unroll
            for (int b = 0; b < 4; ++b) acc[a][b] = 0.f;

#pragma unroll 4
        for (int c4 = 0; c4 < 64; c4 += 4) {
            float xq[4][4], cq[4][4];
#pragma unroll
            for (int i = 0; i < 4; ++i)
                *(float4*)xq[i] = *(const float4*)&xs[c4 + i][4 * mg];   // xq[i][mi]
#pragma unroll
            for (int j = 0; j < 4; ++j)
                *(float4*)cq[j] = *(const float4*)&cs[4 * ng + j][c4];   // cq[j][i]
#pragma unroll
            for (int j = 0; j < 4; ++j)
#pragma unroll
                for (int mi = 0; mi < 4; ++mi)
#pragma unroll
                    for (int i = 0; i < 4; ++i)
                        acc[mi][j] = fmaf(xq[i][mi], cq[j][i], acc[mi][j]);
        }
        __syncthreads();                 // cnorm_s visible; compute done

        // d = cnorm - 2*dot (token-constant |x|^2 dropped: argmin-invariant)
#pragma unroll
        for (int mi = 0; mi < 4; ++mi)
#pragma unroll
            for (int j = 0; j < 4; ++j) {
                float d = fmaf(-2.0f, acc[mi][j], cnorm_s[4 * ng + j]);
                unsigned db = __float_as_uint(d);
                db = (db & 0x80000000u) ? ~db : (db | 0x80000000u);
                unsigned long long cand =
                    ((unsigned long long)db << 32) | (unsigned)(kt * 64 + 4 * ng + j);
                if (cand < bestP[mi]) bestP[mi] = cand;
            }
    }

    // Cross-thread argmin per token (u64 min over 16 n-groups)
#pragma unroll
    for (int mi = 0; mi < 4; ++mi) red[4 * mg + mi][ng] = bestP[mi];
    __syncthreads();
    if (tid < 64) {
        unsigned long long b = red[tid][0];
#pragma unroll
        for (int j = 1; j < 16; ++j) {
            unsigned long long v = red[tid][j];
            if (v < b) b = v;
        }
        int bi = (int)(b & 0xffffffffu);
        ((int*)(ws + WS_IDX))[row * 64 + tid] = bi;   // coalesced
        bi_s[tid] = bi;
    }
    __syncthreads();

    // q gather + transpose: reuse cs as [64][65] (odd stride: both phases 2-way-free)
    float (*qt)[65] = (float(*)[65]) & cs[0][0];
#pragma unroll
    for (int j = 0; j < 16; ++j) {
        int tt = wv * 16 + j;
        qt[lane][tt] = cb[bi_s[tt] * 64 + lane];      // one 256B row per load
    }
    __syncthreads();
#pragma unroll
    for (int j = 0; j < 16; ++j) {
        int c = wv * 16 + j;
        out[xbase + c * HW_ + lane] = qt[c][lane];    // coalesced per channel
    }
}

// K2: block = (channel c, image s). float4/int4 coalesced reads, LDS histogram.
__global__ __launch_bounds__(256) void k_stats(const float* __restrict__ x,
                                               const float* __restrict__ ws_ro,
                                               float* __restrict__ ws) {
    const int* __restrict__ idx = (const int*)(ws_ro + WS_IDX);
    __shared__ float hist[512];
    __shared__ float hcnt[512];

    const int c = blockIdx.x & 63;
    const int s = blockIdx.x >> 6;
    const int tid = threadIdx.x;
    const bool docnt = (c == 0);

    hist[tid] = 0.f; hist[tid + 256] = 0.f;
    hcnt[tid] = 0.f; hcnt[tid + 256] = 0.f;
    __syncthreads();

    const float4* __restrict__ xc4 = (const float4*)(x + s * CHW_ + c * HW_);
    const int4*   __restrict__ id4 = (const int4*)(idx + s * HW_);
#pragma unroll
    for (int it = 0; it < 4; ++it) {
        int i = it * 256 + tid;
        int4   ii = id4[i];            // coalesced 16B, L2-hot
        float4 xv = xc4[i];            // coalesced 16B
        atomicAdd(&hist[ii.x], xv.x);
        atomicAdd(&hist[ii.y], xv.y);
        atomicAdd(&hist[ii.z], xv.z);
        atomicAdd(&hist[ii.w], xv.w);
        if (docnt) {
            atomicAdd(&hcnt[ii.x], 1.0f);
            atomicAdd(&hcnt[ii.y], 1.0f);
            atomicAdd(&hcnt[ii.z], 1.0f);
            atomicAdd(&hcnt[ii.w], 1.0f);
        }
    }
    __syncthreads();

    float* psum = ws + WS_PSUM + s * (K_ * Cc_) + c * K_;
    psum[tid] = hist[tid];
    psum[tid + 256] = hist[tid + 256];
    if (docnt) {
        float* pc = ws + WS_PCNT + s * K_;
        pc[tid] = hcnt[tid];
        pc[tid + 256] = hcnt[tid + 256];
    }
}

// K3: reduce slices, finalize EMA states and codebook_new
__global__ __launch_bounds__(256) void k_final(const float* __restrict__ Ns,
                                               const float* __restrict__ ms,
                                               const float* __restrict__ ws,
                                               float* __restrict__ out) {
    int j = blockIdx.x * 256 + threadIdx.x;  // j = c*512 + k  (coalesced partial reads)
    int c = j >> 9, k = j & 511;

    float s = 0.f, cnt = 0.f;
    for (int sl = 0; sl < S_; ++sl) {
        s   += ws[WS_PSUM + sl * (K_ * Cc_) + j];
        cnt += ws[WS_PCNT + sl * K_ + k];
    }

    const float gamma = 0.99f;
    const float omg   = (float)(1.0 - 0.99);

    bool occ = cnt > 0.0f;
    float Nv = Ns[k];
    float Nnew = occ ? (Nv * gamma + cnt * omg) : Nv;

    int i = k * 64 + c;
    float mv = ms[i];
    float mnew = occ ? (mv * gamma + s * omg) : mv;

    out[OFF_CB + i] = mnew / Nnew;
    out[OFF_M  + i] = mnew;
    if (c == 0) out[OFF_N + k] = Nnew;
}

extern "C" void kernel_launch(void* const* d_in, const int* in_sizes, int n_in,
                              void* d_out, int out_size, void* d_ws, size_t ws_size,
                              hipStream_t stream) {
    const float* x  = (const float*)d_in[0];
    const float* cb = (const float*)d_in[1];
    const float* Ns = (const float*)d_in[2];
    const float* ms = (const float*)d_in[3];
    float* out = (float*)d_out;
    float* ws  = (float*)d_ws;

    hipLaunchKernelGGL(k_assign, dim3(Nn_ * Hh_),   dim3(256), 0, stream, x, cb, ws, out);
    hipLaunchKernelGGL(k_stats,  dim3(S_ * Cc_),    dim3(256), 0, stream, x, ws, ws);
    hipLaunchKernelGGL(k_final,  dim3(32768 / 256), dim3(256), 0, stream, Ns, ms, ws, out);
}

// Round 10
// 282.607 us; speedup vs baseline: 1.1940x; 1.0581x over previous
//
#include <hip/hip_runtime.h>

// Problem constants
static constexpr int Nn_ = 32, Cc_ = 64, Hh_ = 64, Ww_ = 64;
static constexpr int K_ = 512;
static constexpr int HW_ = Hh_ * Ww_;             // 4096
static constexpr int CHW_ = Cc_ * HW_;            // 262144
static constexpr int T_ = Nn_ * Hh_ * Ww_;        // 131072 tokens
static constexpr int OUT_ELEMS = Nn_ * Cc_ * Hh_ * Ww_;  // 8388608
// d_out layout: [out][codebook_new (32768)][N_new (512)][m_new (32768)]
static constexpr int OFF_CB = OUT_ELEMS;
static constexpr int OFF_N  = OUT_ELEMS + 32768;
static constexpr int OFF_M  = OUT_ELEMS + 32768 + 512;

static constexpr int S_ = 32;   // stats slices == images

// ws layout (floats):
// [0, T_)        idx per token (int)
// [WS_PSUM, +S_*512*64)  per-slice partial sums [s][c][k]
// [WS_PCNT, +S_*512)     per-slice partial counts [s][k]
static constexpr int WS_IDX   = 0;
static constexpr int WS_PSUM  = T_ + 512;
static constexpr int WS_PCNT  = WS_PSUM + S_ * K_ * Cc_;

// K1: canonical register-tiled fp32 GEMM, scaled 4x4 -> 8x8 per thread.
// R9 measured: 2 B LDS per FMA -> 8.6 GB ds_read -> LDS-BW-bound at 154us.
// This tile: 16 b128 per 256 FMA = 1 B/FMA -> 4.3 GB -> ~62-82us bound,
// converging with the 54.6us fp32-FMA floor.
// Block = 2 (n,h) rows (M=128 tokens), K=64 staged once; N=512 in 4 tiles
// of 128 restaged per tile. Thread = (4+4 tok) x (4+4 cw) split-quad tile:
// quads at 4mg and 64+4mg keep every LDS access <=2-way (free).
// LDS 71KB caps occupancy at 2 blocks/CU -> allocator has a free 256-VGPR
// budget -> no spill pressure (R8's failure mode). red/qt overlay cs/xs.
__global__ __launch_bounds__(256) void k_assign(const float* __restrict__ x,
                                                const float* __restrict__ cb,
                                                float* __restrict__ ws,
                                                float* __restrict__ out) {
    __shared__ alignas(16) float xs[64][132];   // [channel][token 0..127]
    __shared__ alignas(16) float cs[128][68];   // [codeword-in-tile][channel]
    __shared__ float pcn[2][128];
    __shared__ float cnorm_s[128];
    __shared__ int bi_s[128];

    const int b    = blockIdx.x;        // 0..1023: rows 2b, 2b+1
    const int tid  = threadIdx.x;
    const int mg   = tid & 15;          // token-group
    const int ng   = tid >> 4;          // codeword-group
    const int lane = tid & 63;
    const int wv   = tid >> 6;
    const int row0 = 2 * b, row1 = 2 * b + 1;
    const int xb0 = (row0 >> 6) * CHW_ + (row0 & 63) * Ww_;
    const int xb1 = (row1 >> 6) * CHW_ + (row1 & 63) * Ww_;

    // Stage xs[c][t]: 2048 float4, coalesced global reads.
#pragma unroll
    for (int stp = 0; stp < 8; ++stp) {
        int e = stp * 256 + tid;        // float4 id
        int c = e >> 5, s = e & 31;     // s = token-quad 0..31
        int r = s >> 4, wq = s & 15;
        float4 v = *(const float4*)(x + (r ? xb1 : xb0) + c * HW_ + 4 * wq);
        *(float4*)&xs[c][4 * s] = v;
    }

    unsigned long long bestA[4], bestB[4];   // tokens 4mg+mi / 64+4mg+mi
#pragma unroll
    for (int i = 0; i < 4; ++i) { bestA[i] = ~0ull; bestB[i] = ~0ull; }

#pragma unroll 1
    for (int kt = 0; kt < 4; ++kt) {
        __syncthreads();                 // xs ready (kt=0); cs reusable
        // Stage cs[r][c] for codewords kt*128..+127 (coalesced float4)
#pragma unroll
        for (int stp = 0; stp < 8; ++stp) {
            int e = stp * 256 + tid;
            int rr = e >> 4, cq = e & 15;
            float4 v = *(const float4*)(cb + (kt * 128 + rr) * 64 + 4 * cq);
            *(float4*)&cs[rr][4 * cq] = v;
        }
        __syncthreads();

        // cnorm partials: thread -> (row = tid>>1, half = tid&1), 32 ch each
        {
            int rr = tid >> 1, hf = tid & 1;
            float a = 0.f;
#pragma unroll
            for (int i = 0; i < 8; ++i) {
                float4 v = *(const float4*)&cs[rr][32 * hf + 4 * i];
                a = fmaf(v.x, v.x, a); a = fmaf(v.y, v.y, a);
                a = fmaf(v.z, v.z, a); a = fmaf(v.w, v.w, a);
            }
            pcn[hf][rr] = a;
        }
        __syncthreads();
        if (tid < 128) cnorm_s[tid] = pcn[0][tid] + pcn[1][tid];

        // 4 x 4x4 sub-tiles: (tokA,tokB) x (cwA,cwB)
        float aAA[4][4], aAB[4][4], aBA[4][4], aBB[4][4];
#pragma unroll
        for (int a = 0; a < 4; ++a)
#pragma unroll
            for (int c2 = 0; c2 < 4; ++c2) {
                aAA[a][c2] = 0.f; aAB[a][c2] = 0.f;
                aBA[a][c2] = 0.f; aBB[a][c2] = 0.f;
            }

#pragma unroll 2
        for (int c4 = 0; c4 < 64; c4 += 4) {
            float xA[4][4], xB[4][4], cA[4][4], cB[4][4];
#pragma unroll
            for (int i = 0; i < 4; ++i) {
                *(float4*)xA[i] = *(const float4*)&xs[c4 + i][4 * mg];        // xA[i][mi]
                *(float4*)xB[i] = *(const float4*)&xs[c4 + i][64 + 4 * mg];
            }
#pragma unroll
            for (int j = 0; j < 4; ++j) {
                *(float4*)cA[j] = *(const float4*)&cs[4 * ng + j][c4];        // cA[j][i]
                *(float4*)cB[j] = *(const float4*)&cs[64 + 4 * ng + j][c4];
            }
#pragma unroll
            for (int j = 0; j < 4; ++j)
#pragma unroll
                for (int mi = 0; mi < 4; ++mi)
#pragma unroll
                    for (int i = 0; i < 4; ++i) {
                        aAA[mi][j] = fmaf(xA[i][mi], cA[j][i], aAA[mi][j]);
                        aAB[mi][j] = fmaf(xA[i][mi], cB[j][i], aAB[mi][j]);
                        aBA[mi][j] = fmaf(xB[i][mi], cA[j][i], aBA[mi][j]);
                        aBB[mi][j] = fmaf(xB[i][mi], cB[j][i], aBB[mi][j]);
                    }
        }
        __syncthreads();                 // cnorm_s visible; cs reads done

        // d = cnorm - 2*dot (token-constant |x|^2 dropped: argmin-invariant)
#pragma unroll
        for (int mi = 0; mi < 4; ++mi)
#pragma unroll
            for (int j = 0; j < 4; ++j) {
                int kA = kt * 128 + 4 * ng + j;
                int kB = kA + 64;
                float dAA = fmaf(-2.0f, aAA[mi][j], cnorm_s[4 * ng + j]);
                float dAB = fmaf(-2.0f, aAB[mi][j], cnorm_s[64 + 4 * ng + j]);
                float dBA = fmaf(-2.0f, aBA[mi][j], cnorm_s[4 * ng + j]);
                float dBB = fmaf(-2.0f, aBB[mi][j], cnorm_s[64 + 4 * ng + j]);
                unsigned u;
                unsigned long long cd;
                u = __float_as_uint(dAA); u = (u & 0x80000000u) ? ~u : (u | 0x80000000u);
                cd = ((unsigned long long)u << 32) | (unsigned)kA;
                if (cd < bestA[mi]) bestA[mi] = cd;
                u = __float_as_uint(dAB); u = (u & 0x80000000u) ? ~u : (u | 0x80000000u);
                cd = ((unsigned long long)u << 32) | (unsigned)kB;
                if (cd < bestA[mi]) bestA[mi] = cd;
                u = __float_as_uint(dBA); u = (u & 0x80000000u) ? ~u : (u | 0x80000000u);
                cd = ((unsigned long long)u << 32) | (unsigned)kA;
                if (cd < bestB[mi]) bestB[mi] = cd;
                u = __float_as_uint(dBB); u = (u & 0x80000000u) ? ~u : (u | 0x80000000u);
                cd = ((unsigned long long)u << 32) | (unsigned)kB;
                if (cd < bestB[mi]) bestB[mi] = cd;
            }
    }

    // Cross-thread argmin: red[token][ng] overlays cs (main-loop reads done,
    // last sync above). u64 min == lexicographic (d,k) min == np first-min.
    unsigned long long* red = (unsigned long long*)&cs[0][0];   // [128][17]
#pragma unroll
    for (int mi = 0; mi < 4; ++mi) {
        red[(4 * mg + mi) * 17 + ng] = bestA[mi];
        red[(64 + 4 * mg + mi) * 17 + ng] = bestB[mi];
    }
    __syncthreads();
    if (tid < 128) {
        unsigned long long bm = red[tid * 17 + 0];
#pragma unroll
        for (int j = 1; j < 16; ++j) {
            unsigned long long v = red[tid * 17 + j];
            if (v < bm) bm = v;
        }
        int bi = (int)(bm & 0xffffffffu);
        ((int*)(ws + WS_IDX))[128 * b + tid] = bi;   // coalesced
        bi_s[tid] = bi;
    }
    __syncthreads();

    // q gather + transpose: qt overlays xs (xs reads done)
    float (*qt)[132] = xs;
#pragma unroll
    for (int jj = 0; jj < 32; ++jj) {
        int tt = wv * 32 + jj;
        qt[lane][tt] = cb[bi_s[tt] * 64 + lane];     // one 256B row per load
    }
    __syncthreads();
#pragma unroll
    for (int r = 0; r < 2; ++r)
#pragma unroll
        for (int j = 0; j < 16; ++j) {
            int c = wv * 16 + j;
            out[(r ? xb1 : xb0) + c * HW_ + lane] = qt[c][64 * r + lane];  // coalesced
        }
}

// K2: block = (channel c, image s). float4/int4 coalesced reads, LDS histogram.
__global__ __launch_bounds__(256) void k_stats(const float* __restrict__ x,
                                               const float* __restrict__ ws_ro,
                                               float* __restrict__ ws) {
    const int* __restrict__ idx = (const int*)(ws_ro + WS_IDX);
    __shared__ float hist[512];
    __shared__ float hcnt[512];

    const int c = blockIdx.x & 63;
    const int s = blockIdx.x >> 6;
    const int tid = threadIdx.x;
    const bool docnt = (c == 0);

    hist[tid] = 0.f; hist[tid + 256] = 0.f;
    hcnt[tid] = 0.f; hcnt[tid + 256] = 0.f;
    __syncthreads();

    const float4* __restrict__ xc4 = (const float4*)(x + s * CHW_ + c * HW_);
    const int4*   __restrict__ id4 = (const int4*)(idx + s * HW_);
#pragma unroll
    for (int it = 0; it < 4; ++it) {
        int i = it * 256 + tid;
        int4   ii = id4[i];            // coalesced 16B, L2-hot
        float4 xv = xc4[i];            // coalesced 16B
        atomicAdd(&hist[ii.x], xv.x);
        atomicAdd(&hist[ii.y], xv.y);
        atomicAdd(&hist[ii.z], xv.z);
        atomicAdd(&hist[ii.w], xv.w);
        if (docnt) {
            atomicAdd(&hcnt[ii.x], 1.0f);
            atomicAdd(&hcnt[ii.y], 1.0f);
            atomicAdd(&hcnt[ii.z], 1.0f);
            atomicAdd(&hcnt[ii.w], 1.0f);
        }
    }
    __syncthreads();

    float* psum = ws + WS_PSUM + s * (K_ * Cc_) + c * K_;
    psum[tid] = hist[tid];
    psum[tid + 256] = hist[tid + 256];
    if (docnt) {
        float* pc = ws + WS_PCNT + s * K_;
        pc[tid] = hcnt[tid];
        pc[tid + 256] = hcnt[tid + 256];
    }
}

// K3: reduce slices, finalize EMA states and codebook_new
__global__ __launch_bounds__(256) void k_final(const float* __restrict__ Ns,
                                               const float* __restrict__ ms,
                                               const float* __restrict__ ws,
                                               float* __restrict__ out) {
    int j = blockIdx.x * 256 + threadIdx.x;  // j = c*512 + k  (coalesced partial reads)
    int c = j >> 9, k = j & 511;

    float s = 0.f, cnt = 0.f;
    for (int sl = 0; sl < S_; ++sl) {
        s   += ws[WS_PSUM + sl * (K_ * Cc_) + j];
        cnt += ws[WS_PCNT + sl * K_ + k];
    }

    const float gamma = 0.99f;
    const float omg   = (float)(1.0 - 0.99);

    bool occ = cnt > 0.0f;
    float Nv = Ns[k];
    float Nnew = occ ? (Nv * gamma + cnt * omg) : Nv;

    int i = k * 64 + c;
    float mv = ms[i];
    float mnew = occ ? (mv * gamma + s * omg) : mv;

    out[OFF_CB + i] = mnew / Nnew;
    out[OFF_M  + i] = mnew;
    if (c == 0) out[OFF_N + k] = Nnew;
}

extern "C" void kernel_launch(void* const* d_in, const int* in_sizes, int n_in,
                              void* d_out, int out_size, void* d_ws, size_t ws_size,
                              hipStream_t stream) {
    const float* x  = (const float*)d_in[0];
    const float* cb = (const float*)d_in[1];
    const float* Ns = (const float*)d_in[2];
    const float* ms = (const float*)d_in[3];
    float* out = (float*)d_out;
    float* ws  = (float*)d_ws;

    hipLaunchKernelGGL(k_assign, dim3(1024),        dim3(256), 0, stream, x, cb, ws, out);
    hipLaunchKernelGGL(k_stats,  dim3(S_ * Cc_),    dim3(256), 0, stream, x, ws, ws);
    hipLaunchKernelGGL(k_final,  dim3(32768 / 256), dim3(256), 0, stream, Ns, ms, ws, out);
}